// Round 2
// baseline (75.985 us; speedup 1.0000x reference)
//
#include <hip/hip_runtime.h>

typedef __attribute__((ext_vector_type(8))) short bf16x8;
typedef __attribute__((ext_vector_type(4))) float f32x4;
typedef __attribute__((ext_vector_type(8))) unsigned short u16x8;

#define BB 32
#define NN 1024
#define MM 256
#define HH 128

__device__ __forceinline__ unsigned short f2bf(float f) {
  union { float f; unsigned int u; } c; c.f = f;
  unsigned int u = c.u + 0x7fffu + ((c.u >> 16) & 1u);  // RNE
  return (unsigned short)(u >> 16);
}
__device__ __forceinline__ unsigned int pack2(float lo, float hi) {
  return (unsigned int)f2bf(lo) | ((unsigned int)f2bf(hi) << 16);
}

// ---------------- h transpose: h[B][N][M] f32 -> hT[B][M][N] bf16 ----------------
__global__ __launch_bounds__(256)
void k_transpose_h(const float* __restrict__ hg, unsigned short* __restrict__ hTg) {
  __shared__ unsigned short tile[64][65];
  int bid = blockIdx.x;
  int b = bid >> 6;
  int t = bid & 63;
  int k0 = (t >> 2) << 6;
  int m0 = (t & 3) << 6;
  int tt = threadIdx.x;
  {
    int r = tt >> 2;
    int cg = (tt & 3) << 4;
    const float* src = hg + (((size_t)b * NN + k0 + r) * MM + m0 + cg);
#pragma unroll
    for (int i = 0; i < 4; ++i) {
      float4 v = reinterpret_cast<const float4*>(src)[i];
      tile[r][cg + i * 4 + 0] = f2bf(v.x);
      tile[r][cg + i * 4 + 1] = f2bf(v.y);
      tile[r][cg + i * 4 + 2] = f2bf(v.z);
      tile[r][cg + i * 4 + 3] = f2bf(v.w);
    }
  }
  __syncthreads();
  {
    int mr = tt >> 2;
    int kc = (tt & 3) << 4;
    alignas(16) unsigned short tmp[16];
#pragma unroll
    for (int i = 0; i < 16; ++i) tmp[i] = tile[kc + i][mr];
    unsigned short* dst = hTg + (((size_t)b * MM + m0 + mr) * NN + k0 + kc);
    *reinterpret_cast<u16x8*>(dst)     = *reinterpret_cast<u16x8*>(tmp);
    *reinterpret_cast<u16x8*>(dst + 8) = *reinterpret_cast<u16x8*>(tmp + 8);
  }
}

// ------------- W transposes -------------
__global__ __launch_bounds__(256)
void k_transpose_w(const float* __restrict__ W1, const float* __restrict__ W2,
                   unsigned short* __restrict__ W1T, unsigned short* __restrict__ W2T) {
  int idx = blockIdx.x * 256 + threadIdx.x;
  if (idx < MM * HH) {
    int hc = idx >> 8;
    int m  = idx & 255;
    W1T[idx] = f2bf(W1[m * HH + hc]);
  } else {
    int j = idx - MM * HH;
    int m  = j >> 7;
    int hd = j & 127;
    W2T[j] = f2bf(W2[hd * MM + m]);
  }
}

// ---------------- fused main ----------------
// LDS map: A0@0(16K) A1@16K H0@32K(32K) H1@64K(32K)   [phase 1, dbuf]
//          Kld@0(64K) W1ld@64K(64K)                   [phase 2, after barrier]
//          Cld@0(32K) W2ld@64K(32K)                   [phase 3, after barrier]
#define A0_OFF 0
#define A1_OFF 16384
#define H0_OFF 32768
#define H1_OFF 65536

__device__ __forceinline__ void issueA(const float* src, float4 r[4]) {
#pragma unroll
  for (int i = 0; i < 4; ++i) r[i] = reinterpret_cast<const float4*>(src)[i];
}
__device__ __forceinline__ void issueH(const unsigned short* src, uint4 r[4]) {
#pragma unroll
  for (int i = 0; i < 4; ++i) r[i] = *reinterpret_cast<const uint4*>(src + (size_t)i * 64 * NN);
}
__device__ __forceinline__ float cvtWriteA(char* smem, int arow, int acg, const float4 r[4]) {
  float m0 = fmaxf(fmaxf(r[0].x, r[0].y), fmaxf(r[0].z, r[0].w));
  float m1 = fmaxf(fmaxf(r[1].x, r[1].y), fmaxf(r[1].z, r[1].w));
  float m2 = fmaxf(fmaxf(r[2].x, r[2].y), fmaxf(r[2].z, r[2].w));
  float m3 = fmaxf(fmaxf(r[3].x, r[3].y), fmaxf(r[3].z, r[3].w));
  unsigned int p0 = pack2(r[0].x, r[0].y), p1 = pack2(r[0].z, r[0].w);
  unsigned int p2 = pack2(r[1].x, r[1].y), p3 = pack2(r[1].z, r[1].w);
  unsigned int p4 = pack2(r[2].x, r[2].y), p5 = pack2(r[2].z, r[2].w);
  unsigned int p6 = pack2(r[3].x, r[3].y), p7 = pack2(r[3].z, r[3].w);
  int base = arow * 128;
  int sw   = (arow & 7) << 4;
  *reinterpret_cast<uint4*>(smem + base + ((acg * 2) ^ sw))      = make_uint4(p0, p1, p2, p3);
  *reinterpret_cast<uint4*>(smem + base + ((acg * 2 + 16) ^ sw)) = make_uint4(p4, p5, p6, p7);
  return fmaxf(fmaxf(m0, m1), fmaxf(m2, m3));
}
__device__ __forceinline__ void writeH(char* smem, int tid, const uint4 r[4]) {
  const int hc = (tid & 7) << 3;
#pragma unroll
  for (int i = 0; i < 4; ++i) {
    int hrow = (i << 6) + (tid >> 3);
    *reinterpret_cast<uint4*>(smem + hrow * 128 + ((hc * 2) ^ ((hrow & 7) << 4))) = r[i];
  }
}

#define PIPE_BARRIER() do { \
  asm volatile("s_waitcnt lgkmcnt(0)" ::: "memory"); \
  __builtin_amdgcn_s_barrier(); \
  asm volatile("" ::: "memory"); } while (0)

__global__ __launch_bounds__(512, 1)
void k_fused(const float* __restrict__ Ag, const float* __restrict__ hg,
             const unsigned short* __restrict__ hTg,
             const unsigned short* __restrict__ W1Tg,
             const unsigned short* __restrict__ W2Tg,
             const float* __restrict__ b1g, const float* __restrict__ b2g,
             float* __restrict__ outg) {
  __shared__ __align__(16) char smem[131072];
  __shared__ float smax[128];

  const int tid  = threadIdx.x;
  const int lane = tid & 63;
  const int wid  = tid >> 6;
  const int wr   = wid >> 2;
  const int wc   = wid & 3;
  const int l15  = lane & 15;
  const int lg   = lane >> 4;

  const int bid = blockIdx.x;
  const int b   = bid & 31;           // XCD swizzle: same-batch blocks share bid%8
  const int r0  = (bid >> 5) << 7;

  const float* Ab = Ag + ((size_t)b * NN + r0) * NN;
  const unsigned short* hTb = hTg + (size_t)b * MM * NN;

  f32x4 acc[4][4];
#pragma unroll
  for (int m = 0; m < 4; ++m)
#pragma unroll
    for (int n = 0; n < 4; ++n) acc[m][n] = f32x4{0.f, 0.f, 0.f, 0.f};

  float pmax = -1e30f;
  const int arow = tid >> 2;
  const int acg  = (tid & 3) << 4;
  const float* Asrc = Ab + (size_t)arow * NN + acg;
  const unsigned short* Hsrc = hTb + (size_t)(tid >> 3) * NN + ((tid & 7) << 3);

  float4 a0[4], a1[4];
  uint4  h0[4], h1[4];

  // MFMA consume of one staged K-tile
#define CONSUME(AOFF, HOFF)                                                          \
  do {                                                                               \
    _Pragma("unroll")                                                                \
    for (int kk = 0; kk < 2; ++kk) {                                                 \
      const int kb = (kk * 32 + (lg << 3)) * 2;                                      \
      bf16x8 af[4], bfr[4];                                                          \
      _Pragma("unroll")                                                              \
      for (int m = 0; m < 4; ++m) {                                                  \
        int row = (wr << 6) + (m << 4) + l15;                                        \
        af[m] = *reinterpret_cast<const bf16x8*>(smem + (AOFF) + row * 128 +         \
                                                 (kb ^ ((row & 7) << 4)));           \
      }                                                                              \
      _Pragma("unroll")                                                              \
      for (int n = 0; n < 4; ++n) {                                                  \
        int col = (wc << 6) + (n << 4) + l15;                                        \
        bfr[n] = *reinterpret_cast<const bf16x8*>(smem + (HOFF) + col * 128 +        \
                                                  (kb ^ ((col & 7) << 4)));          \
      }                                                                              \
      _Pragma("unroll")                                                              \
      for (int m = 0; m < 4; ++m)                                                    \
        _Pragma("unroll")                                                            \
        for (int n = 0; n < 4; ++n)                                                  \
          acc[m][n] = __builtin_amdgcn_mfma_f32_16x16x32_bf16(af[m], bfr[n],         \
                                                              acc[m][n], 0, 0, 0);   \
    }                                                                                \
  } while (0)

  // ============ phase 1: k = A @ h, pipelined (16 K-steps of 64) ============
  issueA(Asrc, a0);
  issueH(Hsrc, h0);
  for (int t2 = 0; t2 < 8; ++t2) {
    const int k0 = t2 << 7;
    // even iter t=2*t2: consume buf0, prefetch k0+64 -> (a1,h1)
    issueA(Asrc + k0 + 64, a1);
    issueH(Hsrc + k0 + 64, h1);
    pmax = fmaxf(pmax, cvtWriteA(smem + A0_OFF, arow, acg, a0));
    writeH(smem + H0_OFF, tid, h0);
    PIPE_BARRIER();
    CONSUME(A0_OFF, H0_OFF);
    // odd iter t=2*t2+1: consume buf1, prefetch k0+128 -> (a0,h0)
    if (t2 != 7) {
      issueA(Asrc + k0 + 128, a0);
      issueH(Hsrc + k0 + 128, h0);
    }
    pmax = fmaxf(pmax, cvtWriteA(smem + A1_OFF, arow, acg, a1));
    writeH(smem + H1_OFF, tid, h1);
    PIPE_BARRIER();
    CONSUME(A1_OFF, H1_OFF);
  }
  __syncthreads();  // phase-1 LDS fully retired before aliasing

  // row-max finalize (4 staging threads per row are adjacent lanes)
  {
    float v = pmax;
    v = fmaxf(v, __shfl_xor(v, 1));
    v = fmaxf(v, __shfl_xor(v, 2));
    if ((tid & 3) == 0) smax[arow] = v;
  }

  // write k tile (/3, bf16) -> Kld [128][256] swizzled (rowB=512) at smem+0
  {
    const float inv3 = 1.0f / 3.0f;
#pragma unroll
    for (int m = 0; m < 4; ++m)
#pragma unroll
      for (int n = 0; n < 4; ++n) {
        int col = (wc << 6) + (n << 4) + l15;
#pragma unroll
        for (int j = 0; j < 4; ++j) {
          int row = (wr << 6) + (m << 4) + (lg << 2) + j;
          *reinterpret_cast<unsigned short*>(smem + row * 512 + ((col * 2) ^ ((row & 7) << 4))) =
              f2bf(acc[m][n][j] * inv3);
        }
      }
  }
  // stage W1T [128][256] bf16 -> smem+65536 (rowB=512)
  {
#pragma unroll
    for (int i = 0; i < 8; ++i) {
      int c = (i << 9) + tid;
      int row = c >> 5;
      int bc  = (c & 31) << 4;
      uint4 v = *reinterpret_cast<const uint4*>(W1Tg + ((size_t)c << 3));
      *reinterpret_cast<uint4*>(smem + 65536 + row * 512 + (bc ^ ((row & 7) << 4))) = v;
    }
  }
  __syncthreads();

  // ============ GEMM1: y[128][128] = k @ W1 ============
  f32x4 acc1[4][2];
#pragma unroll
  for (int m = 0; m < 4; ++m)
#pragma unroll
    for (int n = 0; n < 2; ++n) acc1[m][n] = f32x4{0.f, 0.f, 0.f, 0.f};
#pragma unroll
  for (int kk = 0; kk < 8; ++kk) {
    const int kb = (kk * 32 + (lg << 3)) * 2;
    bf16x8 af[4], bfr[2];
#pragma unroll
    for (int m = 0; m < 4; ++m) {
      int row = (wr << 6) + (m << 4) + l15;
      af[m] = *reinterpret_cast<const bf16x8*>(smem + row * 512 + (kb ^ ((row & 7) << 4)));
    }
#pragma unroll
    for (int n = 0; n < 2; ++n) {
      int col = (wc << 5) + (n << 4) + l15;
      bfr[n] = *reinterpret_cast<const bf16x8*>(smem + 65536 + col * 512 + (kb ^ ((col & 7) << 4)));
    }
#pragma unroll
    for (int m = 0; m < 4; ++m)
#pragma unroll
      for (int n = 0; n < 2; ++n)
        acc1[m][n] = __builtin_amdgcn_mfma_f32_16x16x32_bf16(af[m], bfr[n], acc1[m][n], 0, 0, 0);
  }
  __syncthreads();

  // c = relu(y + b1) -> Cld [128][128] bf16 (rowB=256) at smem+0
  {
#pragma unroll
    for (int n = 0; n < 2; ++n) {
      int col = (wc << 5) + (n << 4) + l15;
      float bias = b1g[col];
#pragma unroll
      for (int m = 0; m < 4; ++m)
#pragma unroll
        for (int j = 0; j < 4; ++j) {
          int row = (wr << 6) + (m << 4) + (lg << 2) + j;
          float v = fmaxf(acc1[m][n][j] + bias, 0.f);
          *reinterpret_cast<unsigned short*>(smem + row * 256 + ((col * 2) ^ ((row & 7) << 4))) = f2bf(v);
        }
    }
  }
  // stage W2T [256][128] bf16 -> smem+65536 (rowB=256)
  {
#pragma unroll
    for (int i = 0; i < 8; ++i) {
      int c = (i << 9) + tid;
      int row = c >> 4;
      int bc  = (c & 15) << 4;
      uint4 v = *reinterpret_cast<const uint4*>(W2Tg + ((size_t)c << 3));
      *reinterpret_cast<uint4*>(smem + 65536 + row * 256 + (bc ^ ((row & 7) << 4))) = v;
    }
  }
  __syncthreads();

  // ============ GEMM2: out2[128][256] = c @ W2 ============
  f32x4 acc2[4][4];
#pragma unroll
  for (int m = 0; m < 4; ++m)
#pragma unroll
    for (int n = 0; n < 4; ++n) acc2[m][n] = f32x4{0.f, 0.f, 0.f, 0.f};
#pragma unroll
  for (int kk = 0; kk < 4; ++kk) {
    const int kb = (kk * 32 + (lg << 3)) * 2;
    bf16x8 af[4], bfr[4];
#pragma unroll
    for (int m = 0; m < 4; ++m) {
      int row = (wr << 6) + (m << 4) + l15;
      af[m] = *reinterpret_cast<const bf16x8*>(smem + row * 256 + (kb ^ ((row & 7) << 4)));
    }
#pragma unroll
    for (int n = 0; n < 4; ++n) {
      int col = (wc << 6) + (n << 4) + l15;
      bfr[n] = *reinterpret_cast<const bf16x8*>(smem + 65536 + col * 256 + (kb ^ ((col & 7) << 4)));
    }
#pragma unroll
    for (int m = 0; m < 4; ++m)
#pragma unroll
      for (int n = 0; n < 4; ++n)
        acc2[m][n] = __builtin_amdgcn_mfma_f32_16x16x32_bf16(af[m], bfr[n], acc2[m][n], 0, 0, 0);
  }

  // ============ epilogue: out = (out2+b2)*mask + h*(1-mask) ============
  {
#pragma unroll
    for (int n = 0; n < 4; ++n) {
      int col = (wc << 6) + (n << 4) + l15;
      float b2v = b2g[col];
#pragma unroll
      for (int m = 0; m < 4; ++m)
#pragma unroll
        for (int j = 0; j < 4; ++j) {
          int row = (wr << 6) + (m << 4) + (lg << 2) + j;
          float kv = acc2[m][n][j] + b2v;
          float mask = smax[row];
          size_t gidx = ((size_t)b * NN + r0 + row) * MM + col;
          float hv = hg[gidx];
          outg[gidx] = kv * mask + hv * (1.f - mask);
        }
    }
  }
#undef CONSUME
}

extern "C" void kernel_launch(void* const* d_in, const int* in_sizes, int n_in,
                              void* d_out, int out_size, void* d_ws, size_t ws_size,
                              hipStream_t stream) {
  (void)in_sizes; (void)n_in; (void)out_size; (void)ws_size;
  const float* A  = (const float*)d_in[0];
  const float* h  = (const float*)d_in[1];
  const float* W1 = (const float*)d_in[2];
  const float* b1 = (const float*)d_in[3];
  const float* W2 = (const float*)d_in[4];
  const float* b2 = (const float*)d_in[5];
  float* out = (float*)d_out;

  unsigned short* hT  = (unsigned short*)d_ws;
  unsigned short* W1T = (unsigned short*)((char*)d_ws + (size_t)BB * MM * NN * 2);
  unsigned short* W2T = W1T + MM * HH;

  k_transpose_h<<<BB * 64, 256, 0, stream>>>(h, hT);
  k_transpose_w<<<256, 256, 0, stream>>>(W1, W2, W1T, W2T);
  k_fused<<<BB * 8, 512, 0, stream>>>(A, h, hT, W1T, W2T, b1, b2, out);
}

// Round 3
// 72.835 us; speedup vs baseline: 1.0432x; 1.0432x over previous
//
#include <hip/hip_runtime.h>

typedef __attribute__((ext_vector_type(8))) short bf16x8;
typedef __attribute__((ext_vector_type(4))) float f32x4;
typedef __attribute__((ext_vector_type(8))) unsigned short u16x8;

#define BB 32
#define NN 1024
#define MM 256
#define HH 128

__device__ __forceinline__ unsigned short f2bf(float f) {
  union { float f; unsigned int u; } c; c.f = f;
  unsigned int u = c.u + 0x7fffu + ((c.u >> 16) & 1u);  // RNE
  return (unsigned short)(u >> 16);
}
__device__ __forceinline__ unsigned int pack2(float lo, float hi) {
  return (unsigned int)f2bf(lo) | ((unsigned int)f2bf(hi) << 16);
}

// ---------------- h transpose: h[B][N][M] f32 -> hT[B][M][N] bf16 ----------------
__global__ __launch_bounds__(256)
void k_transpose_h(const float* __restrict__ hg, unsigned short* __restrict__ hTg) {
  __shared__ unsigned short tile[64][65];
  int bid = blockIdx.x;
  int b = bid >> 6;
  int t = bid & 63;
  int k0 = (t >> 2) << 6;
  int m0 = (t & 3) << 6;
  int tt = threadIdx.x;
  {
    int r = tt >> 2;
    int cg = (tt & 3) << 4;
    const float* src = hg + (((size_t)b * NN + k0 + r) * MM + m0 + cg);
#pragma unroll
    for (int i = 0; i < 4; ++i) {
      float4 v = reinterpret_cast<const float4*>(src)[i];
      tile[r][cg + i * 4 + 0] = f2bf(v.x);
      tile[r][cg + i * 4 + 1] = f2bf(v.y);
      tile[r][cg + i * 4 + 2] = f2bf(v.z);
      tile[r][cg + i * 4 + 3] = f2bf(v.w);
    }
  }
  __syncthreads();
  {
    int mr = tt >> 2;
    int kc = (tt & 3) << 4;
    alignas(16) unsigned short tmp[16];
#pragma unroll
    for (int i = 0; i < 16; ++i) tmp[i] = tile[kc + i][mr];
    unsigned short* dst = hTg + (((size_t)b * MM + m0 + mr) * NN + k0 + kc);
    *reinterpret_cast<u16x8*>(dst)     = *reinterpret_cast<u16x8*>(tmp);
    *reinterpret_cast<u16x8*>(dst + 8) = *reinterpret_cast<u16x8*>(tmp + 8);
  }
}

// ------------- W transposes -------------
__global__ __launch_bounds__(256)
void k_transpose_w(const float* __restrict__ W1, const float* __restrict__ W2,
                   unsigned short* __restrict__ W1T, unsigned short* __restrict__ W2T) {
  int idx = blockIdx.x * 256 + threadIdx.x;
  if (idx < MM * HH) {
    int hc = idx >> 8;
    int m  = idx & 255;
    W1T[idx] = f2bf(W1[m * HH + hc]);
  } else {
    int j = idx - MM * HH;
    int m  = j >> 7;
    int hd = j & 127;
    W2T[j] = f2bf(W2[hd * MM + m]);
  }
}

// ---------------- fused main ----------------
// 512 blocks x 256 threads (4 waves, 1x4 over cols). Block tile: 64 rows x 256 cols.
// LDS: phase1 A dbuf [0,16K). phase2 Kld [0,32K) + W1chunk [32K,64K).
//      phase3 Cld [0,16K) + W2chunk [16K,48K). Total 64KB -> 2 blocks/CU.
#define A0_OFF 0
#define A1_OFF 8192
#define KLD_OFF 0
#define W1_OFF 32768
#define CLD_OFF 0
#define W2_OFF 16384

__device__ __forceinline__ void issueA(const float* src, float4 r[4]) {
#pragma unroll
  for (int i = 0; i < 4; ++i) r[i] = reinterpret_cast<const float4*>(src)[i];
}
__device__ __forceinline__ float cvtWriteA(char* dst, int arow, int acg, const float4 r[4]) {
  float m0 = fmaxf(fmaxf(r[0].x, r[0].y), fmaxf(r[0].z, r[0].w));
  float m1 = fmaxf(fmaxf(r[1].x, r[1].y), fmaxf(r[1].z, r[1].w));
  float m2 = fmaxf(fmaxf(r[2].x, r[2].y), fmaxf(r[2].z, r[2].w));
  float m3 = fmaxf(fmaxf(r[3].x, r[3].y), fmaxf(r[3].z, r[3].w));
  unsigned int p0 = pack2(r[0].x, r[0].y), p1 = pack2(r[0].z, r[0].w);
  unsigned int p2 = pack2(r[1].x, r[1].y), p3 = pack2(r[1].z, r[1].w);
  unsigned int p4 = pack2(r[2].x, r[2].y), p5 = pack2(r[2].z, r[2].w);
  unsigned int p6 = pack2(r[3].x, r[3].y), p7 = pack2(r[3].z, r[3].w);
  int base = arow * 128;
  int sw   = (arow & 7) << 4;
  *reinterpret_cast<uint4*>(dst + base + ((acg * 2) ^ sw))      = make_uint4(p0, p1, p2, p3);
  *reinterpret_cast<uint4*>(dst + base + ((acg * 2 + 16) ^ sw)) = make_uint4(p4, p5, p6, p7);
  return fmaxf(fmaxf(m0, m1), fmaxf(m2, m3));
}

__global__ __launch_bounds__(256, 2)
void k_fused(const float* __restrict__ Ag, const float* __restrict__ hg,
             const unsigned short* __restrict__ hTg,
             const unsigned short* __restrict__ W1Tg,
             const unsigned short* __restrict__ W2Tg,
             const float* __restrict__ b1g, const float* __restrict__ b2g,
             float* __restrict__ outg) {
  __shared__ __align__(16) char smem[65536];
  __shared__ float smax[64];

  const int tid  = threadIdx.x;
  const int lane = tid & 63;
  const int wid  = tid >> 6;       // 0..3
  const int l15  = lane & 15;
  const int lg   = lane >> 4;      // 0..3
  const int wcol = wid << 6;       // 0,64,128,192

  const int bid = blockIdx.x;
  const int b   = bid & 31;        // same-batch blocks share bid%8 -> same XCD
  const int r0  = (bid >> 5) << 6; // 16 row-blocks of 64

  const float* Ab = Ag + ((size_t)b * NN + r0) * NN;
  const unsigned short* hTb = hTg + (size_t)b * MM * NN;

  f32x4 acc[4][4];
#pragma unroll
  for (int m = 0; m < 4; ++m)
#pragma unroll
    for (int n = 0; n < 4; ++n) acc[m][n] = f32x4{0.f, 0.f, 0.f, 0.f};

  float pmax = -1e30f;
  const int arow = tid >> 2;          // 0..63
  const int acg  = (tid & 3) << 4;    // 0,16,32,48 (f32 col)
  const float* Asrc = Ab + (size_t)arow * NN + acg;

  // H fragments loaded straight from L2-resident hT (no LDS).
#define LOADH(H, K0)                                                                 \
  do {                                                                               \
    _Pragma("unroll")                                                                \
    for (int kk = 0; kk < 2; ++kk)                                                   \
      _Pragma("unroll")                                                              \
      for (int n = 0; n < 4; ++n)                                                    \
        H[kk][n] = *reinterpret_cast<const bf16x8*>(                                 \
            hTb + (size_t)(wcol + (n << 4) + l15) * NN + (K0) + kk * 32 + (lg << 3)); \
  } while (0)

#define CONS(AOFF, H)                                                                \
  do {                                                                               \
    _Pragma("unroll")                                                                \
    for (int kk = 0; kk < 2; ++kk) {                                                 \
      bf16x8 af[4];                                                                  \
      _Pragma("unroll")                                                              \
      for (int m = 0; m < 4; ++m) {                                                  \
        int row = (m << 4) + l15;                                                    \
        af[m] = *reinterpret_cast<const bf16x8*>(                                    \
            smem + (AOFF) + row * 128 + ((((kk * 32 + (lg << 3)) * 2)) ^ ((row & 7) << 4))); \
      }                                                                              \
      _Pragma("unroll")                                                              \
      for (int m = 0; m < 4; ++m)                                                    \
        _Pragma("unroll")                                                            \
        for (int n = 0; n < 4; ++n)                                                  \
          acc[m][n] = __builtin_amdgcn_mfma_f32_16x16x32_bf16(af[m], H[kk][n],       \
                                                              acc[m][n], 0, 0, 0);   \
    }                                                                                \
  } while (0)

  float4 ar0[4], ar1[4];
  bf16x8 h0[2][4], h1[2][4];

  // -------- prologue --------
  issueA(Asrc, ar0);
  issueA(Asrc + 64, ar1);
  LOADH(h0, 0);
  LOADH(h1, 64);
  pmax = fmaxf(pmax, cvtWriteA(smem + A0_OFF, arow, acg, ar0));
  __syncthreads();  // buf0 ready (step 0)

  // -------- phase 1: 16 K-steps of 64, one barrier per step --------
  for (int t2 = 0; t2 < 8; ++t2) {
    const int kbase = t2 << 7;  // k of even step t=2*t2
    // even step t: consume buf0/h0
    if (t2 < 7) issueA(Asrc + kbase + 128, ar0);            // A(t+2)
    CONS(A0_OFF, h0);
    pmax = fmaxf(pmax, cvtWriteA(smem + A1_OFF, arow, acg, ar1));  // A(t+1) -> buf1
    if (t2 < 7) LOADH(h0, kbase + 128);                     // H(t+2)
    __syncthreads();
    // odd step t+1: consume buf1/h1
    if (t2 < 7) issueA(Asrc + kbase + 192, ar1);            // A(t+3)
    CONS(A1_OFF, h1);
    if (t2 < 7) {
      pmax = fmaxf(pmax, cvtWriteA(smem + A0_OFF, arow, acg, ar0));  // A(t+2) -> buf0
      LOADH(h1, kbase + 192);                               // H(t+3)
    }
    __syncthreads();
  }

  // -------- row-max finalize (4 staging threads per row are adjacent lanes) --------
  {
    float v = pmax;
    v = fmaxf(v, __shfl_xor(v, 1));
    v = fmaxf(v, __shfl_xor(v, 2));
    if ((tid & 3) == 0) smax[arow] = v;
  }

  // -------- write k tile (/3, bf16) -> Kld [64][512B] XOR, stage W1 chunk0 --------
  {
    const float inv3 = 1.0f / 3.0f;
#pragma unroll
    for (int m = 0; m < 4; ++m)
#pragma unroll
      for (int n = 0; n < 4; ++n) {
        int col = wcol + (n << 4) + l15;
#pragma unroll
        for (int j = 0; j < 4; ++j) {
          int row = (m << 4) + (lg << 2) + j;
          *reinterpret_cast<unsigned short*>(smem + KLD_OFF + row * 512 +
                                             ((col * 2) ^ ((row & 7) << 4))) =
              f2bf(acc[m][n][j] * inv3);
        }
      }
  }
  {
    int row = tid >> 1, half = tid & 1;
#pragma unroll
    for (int i = 0; i < 8; ++i) {
      uint4 v = *reinterpret_cast<const uint4*>(W1Tg + row * 256 + half * 64 + i * 8);
      *reinterpret_cast<uint4*>(smem + W1_OFF + row * 256 +
                                ((half * 128 + i * 16) ^ ((row & 7) << 4))) = v;
    }
  }
  __syncthreads();

  // -------- GEMM1: y[64][128] = k @ W1, K=256 in 2 chunks of 128 --------
  f32x4 acc1[4][2];
#pragma unroll
  for (int m = 0; m < 4; ++m)
#pragma unroll
    for (int n = 0; n < 2; ++n) acc1[m][n] = f32x4{0.f, 0.f, 0.f, 0.f};
  const int wcol1 = wid << 5;  // 0,32,64,96
#pragma unroll
  for (int c = 0; c < 2; ++c) {
    if (c == 1) {
      __syncthreads();  // done reading chunk0
      int row = tid >> 1, half = tid & 1;
#pragma unroll
      for (int i = 0; i < 8; ++i) {
        uint4 v = *reinterpret_cast<const uint4*>(W1Tg + row * 256 + 128 + half * 64 + i * 8);
        *reinterpret_cast<uint4*>(smem + W1_OFF + row * 256 +
                                  ((half * 128 + i * 16) ^ ((row & 7) << 4))) = v;
      }
      __syncthreads();
    }
#pragma unroll
    for (int kq = 0; kq < 4; ++kq) {
      const int kabs = (c * 4 + kq) * 32 + (lg << 3);  // absolute k in 0..255
      const int kloc = kq * 32 + (lg << 3);            // k within chunk
      bf16x8 af[4], bfr[2];
#pragma unroll
      for (int m = 0; m < 4; ++m) {
        int row = (m << 4) + l15;
        af[m] = *reinterpret_cast<const bf16x8*>(smem + KLD_OFF + row * 512 +
                                                 ((kabs * 2) ^ ((row & 7) << 4)));
      }
#pragma unroll
      for (int n = 0; n < 2; ++n) {
        int col = wcol1 + (n << 4) + l15;
        bfr[n] = *reinterpret_cast<const bf16x8*>(smem + W1_OFF + col * 256 +
                                                  ((kloc * 2) ^ ((col & 7) << 4)));
      }
#pragma unroll
      for (int m = 0; m < 4; ++m)
#pragma unroll
        for (int n = 0; n < 2; ++n)
          acc1[m][n] = __builtin_amdgcn_mfma_f32_16x16x32_bf16(af[m], bfr[n], acc1[m][n], 0, 0, 0);
    }
  }
  __syncthreads();  // done reading Kld / W1

  // -------- c = relu(y+b1) -> Cld [64][256B] XOR; stage W2 chunk0 --------
  {
#pragma unroll
    for (int n = 0; n < 2; ++n) {
      int col = wcol1 + (n << 4) + l15;
      float bias = b1g[col];
#pragma unroll
      for (int m = 0; m < 4; ++m)
#pragma unroll
        for (int j = 0; j < 4; ++j) {
          int row = (m << 4) + (lg << 2) + j;
          float v = fmaxf(acc1[m][n][j] + bias, 0.f);
          *reinterpret_cast<unsigned short*>(smem + CLD_OFF + row * 256 +
                                             ((col * 2) ^ ((row & 7) << 4))) = f2bf(v);
        }
    }
  }
  {
#pragma unroll
    for (int i = 0; i < 8; ++i) {
      uint4 v = *reinterpret_cast<const uint4*>(W2Tg + tid * 128 + i * 8);
      *reinterpret_cast<uint4*>(smem + W2_OFF + tid * 128 +
                                ((i * 16) ^ ((tid & 7) << 4))) = v;
    }
  }
  __syncthreads();

  // -------- GEMM2: out2[64][256] = c @ W2, K=128 in 2 chunks of 64 --------
  f32x4 acc2[4][4];
#pragma unroll
  for (int m = 0; m < 4; ++m)
#pragma unroll
    for (int n = 0; n < 4; ++n) acc2[m][n] = f32x4{0.f, 0.f, 0.f, 0.f};
#pragma unroll
  for (int c = 0; c < 2; ++c) {
    if (c == 1) {
      __syncthreads();
#pragma unroll
      for (int i = 0; i < 8; ++i) {
        uint4 v = *reinterpret_cast<const uint4*>(W2Tg + tid * 128 + 64 + i * 8);
        *reinterpret_cast<uint4*>(smem + W2_OFF + tid * 128 +
                                  ((i * 16) ^ ((tid & 7) << 4))) = v;
      }
      __syncthreads();
    }
#pragma unroll
    for (int kq = 0; kq < 2; ++kq) {
      const int kabs = (c * 2 + kq) * 32 + (lg << 3);  // 0..127
      const int kloc = kq * 32 + (lg << 3);            // 0..63
      bf16x8 af[4], bfr[4];
#pragma unroll
      for (int m = 0; m < 4; ++m) {
        int row = (m << 4) + l15;
        af[m] = *reinterpret_cast<const bf16x8*>(smem + CLD_OFF + row * 256 +
                                                 ((kabs * 2) ^ ((row & 7) << 4)));
      }
#pragma unroll
      for (int n = 0; n < 4; ++n) {
        int col = wcol + (n << 4) + l15;
        bfr[n] = *reinterpret_cast<const bf16x8*>(smem + W2_OFF + col * 128 +
                                                  ((kloc * 2) ^ ((col & 7) << 4)));
      }
#pragma unroll
      for (int m = 0; m < 4; ++m)
#pragma unroll
        for (int n = 0; n < 4; ++n)
          acc2[m][n] = __builtin_amdgcn_mfma_f32_16x16x32_bf16(af[m], bfr[n], acc2[m][n], 0, 0, 0);
    }
  }

  // -------- epilogue: out = (out2+b2)*mask + h*(1-mask) --------
  {
#pragma unroll
    for (int n = 0; n < 4; ++n) {
      int col = wcol + (n << 4) + l15;
      float b2v = b2g[col];
#pragma unroll
      for (int m = 0; m < 4; ++m)
#pragma unroll
        for (int j = 0; j < 4; ++j) {
          int row = (m << 4) + (lg << 2) + j;
          float kv = acc2[m][n][j] + b2v;
          float mask = smax[row];
          size_t gidx = ((size_t)b * NN + r0 + row) * MM + col;
          float hv = hg[gidx];
          outg[gidx] = kv * mask + hv * (1.f - mask);
        }
    }
  }
#undef CONS
#undef LOADH
}

extern "C" void kernel_launch(void* const* d_in, const int* in_sizes, int n_in,
                              void* d_out, int out_size, void* d_ws, size_t ws_size,
                              hipStream_t stream) {
  (void)in_sizes; (void)n_in; (void)out_size; (void)ws_size;
  const float* A  = (const float*)d_in[0];
  const float* h  = (const float*)d_in[1];
  const float* W1 = (const float*)d_in[2];
  const float* b1 = (const float*)d_in[3];
  const float* W2 = (const float*)d_in[4];
  const float* b2 = (const float*)d_in[5];
  float* out = (float*)d_out;

  unsigned short* hT  = (unsigned short*)d_ws;
  unsigned short* W1T = (unsigned short*)((char*)d_ws + (size_t)BB * MM * NN * 2);
  unsigned short* W2T = W1T + MM * HH;

  k_transpose_h<<<BB * 64, 256, 0, stream>>>(h, hT);
  k_transpose_w<<<256, 256, 0, stream>>>(W1, W2, W1T, W2T);
  k_fused<<<BB * 16, 256, 0, stream>>>(A, h, hT, W1T, W2T, b1, b2, out);
}